// Round 1
// baseline (1058.924 us; speedup 1.0000x reference)
//
#include <hip/hip_runtime.h>
#include <math.h>

#define N_ELEMS 1000000
#define EPS_IOU 1e-6f

__global__ void zero_out_kernel(float* out) { out[0] = 0.0f; }

__global__ __launch_bounds__(256) void rot_iou_loss_kernel(
    const float* __restrict__ pred, const float* __restrict__ target,
    float* __restrict__ out, int n, float inv_n) {
  int i = blockIdx.x * blockDim.x + threadIdx.x;
  float loss = 0.0f;
  if (i < n) {
    // ---- load boxes (x, y, w, h, angle) ----
    const float x1 = pred[i * 5 + 0], y1 = pred[i * 5 + 1];
    const float w1 = pred[i * 5 + 2], h1 = pred[i * 5 + 3];
    const float t1 = pred[i * 5 + 4];
    const float x2 = target[i * 5 + 0], y2 = target[i * 5 + 1];
    const float w2 = target[i * 5 + 2], h2 = target[i * 5 + 3];
    const float t2 = target[i * 5 + 4];

    const float c1 = cosf(t1), s1 = sinf(t1);
    const float c2 = cosf(t2), s2 = sinf(t2);

    // ---- corners (order: (-w,-h), (w,-h), (w,h), (-w,h)) * 0.5 ----
    float C1x[4], C1y[4], C2x[4], C2y[4];
    {
      const float dxs[4] = {-0.5f * w1, 0.5f * w1, 0.5f * w1, -0.5f * w1};
      const float dys[4] = {-0.5f * h1, -0.5f * h1, 0.5f * h1, 0.5f * h1};
#pragma unroll
      for (int k = 0; k < 4; ++k) {
        C1x[k] = x1 + dxs[k] * c1 - dys[k] * s1;
        C1y[k] = y1 + dxs[k] * s1 + dys[k] * c1;
      }
      const float ex[4] = {-0.5f * w2, 0.5f * w2, 0.5f * w2, -0.5f * w2};
      const float ey[4] = {-0.5f * h2, -0.5f * h2, 0.5f * h2, 0.5f * h2};
#pragma unroll
      for (int k = 0; k < 4; ++k) {
        C2x[k] = x2 + ex[k] * c2 - ey[k] * s2;
        C2y[k] = y2 + ex[k] * s2 + ey[k] * c2;
      }
    }

    // ---- edge vectors r (box1), s (box2): r[k] = C[(k+1)%4] - C[k] ----
    float rx[4], ry[4], sx[4], sy[4];
#pragma unroll
    for (int k = 0; k < 4; ++k) {
      rx[k] = C1x[(k + 1) & 3] - C1x[k];
      ry[k] = C1y[(k + 1) & 3] - C1y[k];
      sx[k] = C2x[(k + 1) & 3] - C2x[k];
      sy[k] = C2y[(k + 1) & 3] - C2y[k];
    }

    // ---- 24 candidate points + mask ----
    float px[24], py[24];
    bool msk[24];

    // 16 segment-segment intersections, index j*4+k
#pragma unroll
    for (int j = 0; j < 4; ++j) {
#pragma unroll
      for (int k = 0; k < 4; ++k) {
        const float den = rx[j] * sy[k] - ry[j] * sx[k];
        const float den_safe = (fabsf(den) < 1e-12f) ? 1.0f : den;
        const float qpx = C2x[k] - C1x[j];
        const float qpy = C2y[k] - C1y[j];
        const float t = (qpx * sy[k] - qpy * sx[k]) / den_safe;
        const float u = (qpx * ry[j] - qpy * rx[j]) / den_safe;
        const bool ok = (fabsf(den) > 1e-12f) && (t >= 0.0f) && (t <= 1.0f) &&
                        (u >= 0.0f) && (u <= 1.0f);
        const int idx = j * 4 + k;
        px[idx] = C1x[j] + t * rx[j];
        py[idx] = C1y[j] + t * ry[j];
        msk[idx] = ok;
      }
    }

    // corners of box1 inside box2 (indices 16..19)
#pragma unroll
    for (int k = 0; k < 4; ++k) {
      const float relx = C1x[k] - x2, rely = C1y[k] - y2;
      const float lx = relx * c2 + rely * s2;
      const float ly = -relx * s2 + rely * c2;
      px[16 + k] = C1x[k];
      py[16 + k] = C1y[k];
      msk[16 + k] = (fabsf(lx) <= 0.5f * w2 + 1e-5f) && (fabsf(ly) <= 0.5f * h2 + 1e-5f);
    }
    // corners of box2 inside box1 (indices 20..23)
#pragma unroll
    for (int k = 0; k < 4; ++k) {
      const float relx = C2x[k] - x1, rely = C2y[k] - y1;
      const float lx = relx * c1 + rely * s1;
      const float ly = -relx * s1 + rely * c1;
      px[20 + k] = C2x[k];
      py[20 + k] = C2y[k];
      msk[20 + k] = (fabsf(lx) <= 0.5f * w1 + 1e-5f) && (fabsf(ly) <= 0.5f * h1 + 1e-5f);
    }

    // ---- masked count and centroid ----
    float cnt = 0.0f, cx = 0.0f, cy = 0.0f;
#pragma unroll
    for (int k = 0; k < 24; ++k) {
      const float m = msk[k] ? 1.0f : 0.0f;
      cnt += m;
      cx += px[k] * m;
      cy += py[k] * m;
    }
    const float denom = fmaxf(cnt, 1.0f);
    cx /= denom;
    cy /= denom;

    // ---- angles (sentinel 1e9 for unmasked) ----
    float ang[24];
#pragma unroll
    for (int k = 0; k < 24; ++k) {
      ang[k] = msk[k] ? atan2f(py[k] - cy, px[k] - cx) : 1e9f;
    }

    // ---- odd-even transposition sort (24 passes), static indices only ----
#pragma unroll
    for (int pass = 0; pass < 24; ++pass) {
#pragma unroll
      for (int k = (pass & 1); k + 1 < 24; k += 2) {
        const bool sw = ang[k] > ang[k + 1];
        const float ta = sw ? ang[k + 1] : ang[k];
        const float tb = sw ? ang[k] : ang[k + 1];
        ang[k] = ta; ang[k + 1] = tb;
        const float xa = sw ? px[k + 1] : px[k];
        const float xb = sw ? px[k] : px[k + 1];
        px[k] = xa; px[k + 1] = xb;
        const float ya = sw ? py[k + 1] : py[k];
        const float yb = sw ? py[k] : py[k + 1];
        py[k] = ya; py[k + 1] = yb;
      }
    }

    // ---- replace unmasked (ang == 1e9) with first point ----
    const float fx = px[0], fy = py[0];
#pragma unroll
    for (int k = 0; k < 24; ++k) {
      const bool m = ang[k] < 1e9f;  // masked points have angle <= pi
      px[k] = m ? px[k] : fx;
      py[k] = m ? py[k] : fy;
    }

    // ---- shoelace ----
    float acc = 0.0f;
#pragma unroll
    for (int k = 0; k < 24; ++k) {
      const int kn = (k + 1) % 24;
      acc += px[k] * py[kn] - py[k] * px[kn];
    }
    const float area = 0.5f * fabsf(acc);
    const float inter = (cnt >= 3.0f) ? area : 0.0f;

    const float a1 = w1 * h1;
    const float a2 = w2 * h2;
    float iou = inter / (a1 + a2 - inter);
    iou = fmaxf(iou, EPS_IOU);
    loss = 1.0f - iou * iou * iou;  // alpha = 3
  }

  // ---- reduction: wave shuffle -> LDS -> one atomic per block ----
#pragma unroll
  for (int off = 32; off > 0; off >>= 1) loss += __shfl_down(loss, off, 64);

  __shared__ float wsum[4];  // 256 threads / 64-lane waves
  const int lane = threadIdx.x & 63;
  const int wid = threadIdx.x >> 6;
  if (lane == 0) wsum[wid] = loss;
  __syncthreads();
  if (threadIdx.x == 0) {
    const float bsum = wsum[0] + wsum[1] + wsum[2] + wsum[3];
    atomicAdd(out, bsum * inv_n);
  }
}

extern "C" void kernel_launch(void* const* d_in, const int* in_sizes, int n_in,
                              void* d_out, int out_size, void* d_ws, size_t ws_size,
                              hipStream_t stream) {
  const float* pred = (const float*)d_in[0];
  const float* target = (const float*)d_in[1];
  float* out = (float*)d_out;
  const int n = in_sizes[0] / 5;

  zero_out_kernel<<<1, 1, 0, stream>>>(out);
  const int block = 256;
  const int grid = (n + block - 1) / block;
  rot_iou_loss_kernel<<<grid, block, 0, stream>>>(pred, target, out, n,
                                                  1.0f / (float)n);
}

// Round 2
// 124.325 us; speedup vs baseline: 8.5173x; 8.5173x over previous
//
#include <hip/hip_runtime.h>
#include <math.h>

#define EPS_IOU 1e-6f

__global__ void zero_out_kernel(float* out) { out[0] = 0.0f; }

// Clip edge p0 + t*d, t in [0,1], against rotated rect (center rc, axes
// u=(ux,uy), v=(-uy,ux), half-extents hw,hh). Returns clipped length fraction.
__device__ __forceinline__ float clip_len(float p0x, float p0y, float dx, float dy,
                                          float rcx, float rcy, float ux, float uy,
                                          float hw, float hh) {
  const float rx = p0x - rcx, ry = p0y - rcy;
  const float bu = rx * ux + ry * uy;    // position along u
  const float bv = -rx * uy + ry * ux;   // position along v
  const float au = dx * ux + dy * uy;    // direction along u
  const float av = -dx * uy + dy * ux;   // direction along v
  const float iu = __builtin_amdgcn_rcpf(au);  // +-inf when au == 0 (slab-parallel)
  const float iv = __builtin_amdgcn_rcpf(av);
  const float t0 = (-hw - bu) * iu;
  const float t1 = (hw - bu) * iu;
  const float t2 = (-hh - bv) * iv;
  const float t3 = (hh - bv) * iv;
  // IEEE fmin/fmax drop NaN (0*inf grazing case) -> empty interval, measure-zero.
  const float lo = fmaxf(fmaxf(fminf(t0, t1), fminf(t2, t3)), 0.0f);
  const float hi = fminf(fminf(fmaxf(t0, t1), fmaxf(t2, t3)), 1.0f);
  return fmaxf(hi - lo, 0.0f);
}

__global__ __launch_bounds__(256) void rot_iou_loss_kernel(
    const float* __restrict__ pred, const float* __restrict__ target,
    float* __restrict__ out, int n, float inv_n) {
  int i = blockIdx.x * blockDim.x + threadIdx.x;
  float loss = 0.0f;
  if (i < n) {
    const float x1 = pred[i * 5 + 0], y1 = pred[i * 5 + 1];
    const float w1 = pred[i * 5 + 2], h1 = pred[i * 5 + 3];
    const float t1 = pred[i * 5 + 4];
    const float x2 = target[i * 5 + 0], y2 = target[i * 5 + 1];
    const float w2 = target[i * 5 + 2], h2 = target[i * 5 + 3];
    const float t2 = target[i * 5 + 4];

    float s1, c1, s2, c2;
    __sincosf(t1, &s1, &c1);
    __sincosf(t2, &s2, &c2);

    // common origin near both boxes for fp32 headroom in cross products
    const float ox = 0.5f * (x1 + x2), oy = 0.5f * (y1 + y2);
    const float a1x = x1 - ox, a1y = y1 - oy;   // center of A rel origin
    const float a2x = x2 - ox, a2y = y2 - oy;   // center of B rel origin

    const float hw1 = 0.5f * w1, hh1 = 0.5f * h1;
    const float hw2 = 0.5f * w2, hh2 = 0.5f * h2;

    // corners (CCW): (-w,-h),(w,-h),(w,h),(-w,h) * 0.5, rotated, rel origin
    float Ax[4], Ay[4], Bx[4], By[4];
    {
      const float dxs1[4] = {-hw1, hw1, hw1, -hw1};
      const float dys1[4] = {-hh1, -hh1, hh1, hh1};
      const float dxs2[4] = {-hw2, hw2, hw2, -hw2};
      const float dys2[4] = {-hh2, -hh2, hh2, hh2};
#pragma unroll
      for (int k = 0; k < 4; ++k) {
        Ax[k] = a1x + dxs1[k] * c1 - dys1[k] * s1;
        Ay[k] = a1y + dxs1[k] * s1 + dys1[k] * c1;
        Bx[k] = a2x + dxs2[k] * c2 - dys2[k] * s2;
        By[k] = a2y + dxs2[k] * s2 + dys2[k] * c2;
      }
    }

    // Green's theorem over boundary of (A ∩ B):
    //   area = 1/2 * [ sum over edges of A of cross(p0,d)*len_inside_B
    //                + sum over edges of B of cross(p0,d)*len_inside_A ]
    float acc = 0.0f;
#pragma unroll
    for (int k = 0; k < 4; ++k) {
      const int kn = (k + 1) & 3;
      // edge of A clipped against B
      {
        const float dx = Ax[kn] - Ax[k], dy = Ay[kn] - Ay[k];
        const float len = clip_len(Ax[k], Ay[k], dx, dy, a2x, a2y, c2, s2, hw2, hh2);
        acc += (Ax[k] * dy - Ay[k] * dx) * len;
      }
      // edge of B clipped against A
      {
        const float dx = Bx[kn] - Bx[k], dy = By[kn] - By[k];
        const float len = clip_len(Bx[k], By[k], dx, dy, a1x, a1y, c1, s1, hw1, hh1);
        acc += (Bx[k] * dy - By[k] * dx) * len;
      }
    }
    const float inter = fmaxf(0.5f * acc, 0.0f);

    const float ar1 = w1 * h1;
    const float ar2 = w2 * h2;
    float iou = inter / (ar1 + ar2 - inter);
    iou = fmaxf(iou, EPS_IOU);
    loss = 1.0f - iou * iou * iou;  // alpha = 3
  }

  // reduction: wave shuffle -> LDS -> one atomic per block
#pragma unroll
  for (int off = 32; off > 0; off >>= 1) loss += __shfl_down(loss, off, 64);

  __shared__ float wsum[4];
  const int lane = threadIdx.x & 63;
  const int wid = threadIdx.x >> 6;
  if (lane == 0) wsum[wid] = loss;
  __syncthreads();
  if (threadIdx.x == 0) {
    const float bsum = wsum[0] + wsum[1] + wsum[2] + wsum[3];
    atomicAdd(out, bsum * inv_n);
  }
}

extern "C" void kernel_launch(void* const* d_in, const int* in_sizes, int n_in,
                              void* d_out, int out_size, void* d_ws, size_t ws_size,
                              hipStream_t stream) {
  const float* pred = (const float*)d_in[0];
  const float* target = (const float*)d_in[1];
  float* out = (float*)d_out;
  const int n = in_sizes[0] / 5;

  zero_out_kernel<<<1, 1, 0, stream>>>(out);
  const int block = 256;
  const int grid = (n + block - 1) / block;
  rot_iou_loss_kernel<<<grid, block, 0, stream>>>(pred, target, out, n,
                                                  1.0f / (float)n);
}

// Round 3
// 102.701 us; speedup vs baseline: 10.3107x; 1.2106x over previous
//
#include <hip/hip_runtime.h>
#include <math.h>

#define EPS_IOU 1e-6f
#define BLOCK 256
#define EPB 512  // elements (box pairs) per block = BLOCK * 2

__global__ void zero_out_kernel(float* out) { out[0] = 0.0f; }

// Clip edge p0 + t*d, t in [0,1], against rotated rect (center rc, axes
// u=(ux,uy), v=(-uy,ux), half-extents hw,hh). Returns clipped length fraction.
__device__ __forceinline__ float clip_len(float p0x, float p0y, float dx, float dy,
                                          float rcx, float rcy, float ux, float uy,
                                          float hw, float hh) {
  const float rx = p0x - rcx, ry = p0y - rcy;
  const float bu = rx * ux + ry * uy;
  const float bv = -rx * uy + ry * ux;
  const float au = dx * ux + dy * uy;
  const float av = -dx * uy + dy * ux;
  const float iu = __builtin_amdgcn_rcpf(au);  // +-inf when au == 0
  const float iv = __builtin_amdgcn_rcpf(av);
  const float t0 = (-hw - bu) * iu;
  const float t1 = (hw - bu) * iu;
  const float t2 = (-hh - bv) * iv;
  const float t3 = (hh - bv) * iv;
  // IEEE fmin/fmax drop NaN (0*inf grazing) -> empty interval, measure-zero.
  const float lo = fmaxf(fmaxf(fminf(t0, t1), fminf(t2, t3)), 0.0f);
  const float hi = fminf(fminf(fmaxf(t0, t1), fmaxf(t2, t3)), 1.0f);
  return fmaxf(hi - lo, 0.0f);
}

__device__ __forceinline__ float pair_loss(const float* __restrict__ b1,
                                           const float* __restrict__ b2) {
  const float x1 = b1[0], y1 = b1[1], w1 = b1[2], h1 = b1[3], t1 = b1[4];
  const float x2 = b2[0], y2 = b2[1], w2 = b2[2], h2 = b2[3], t2 = b2[4];

  float s1, c1, s2, c2;
  __sincosf(t1, &s1, &c1);
  __sincosf(t2, &s2, &c2);

  // common origin near both boxes for fp32 headroom in cross products
  const float ox = 0.5f * (x1 + x2), oy = 0.5f * (y1 + y2);
  const float a1x = x1 - ox, a1y = y1 - oy;
  const float a2x = x2 - ox, a2y = y2 - oy;

  const float hw1 = 0.5f * w1, hh1 = 0.5f * h1;
  const float hw2 = 0.5f * w2, hh2 = 0.5f * h2;

  float Ax[4], Ay[4], Bx[4], By[4];
  {
    const float dxs1[4] = {-hw1, hw1, hw1, -hw1};
    const float dys1[4] = {-hh1, -hh1, hh1, hh1};
    const float dxs2[4] = {-hw2, hw2, hw2, -hw2};
    const float dys2[4] = {-hh2, -hh2, hh2, hh2};
#pragma unroll
    for (int k = 0; k < 4; ++k) {
      Ax[k] = a1x + dxs1[k] * c1 - dys1[k] * s1;
      Ay[k] = a1y + dxs1[k] * s1 + dys1[k] * c1;
      Bx[k] = a2x + dxs2[k] * c2 - dys2[k] * s2;
      By[k] = a2y + dxs2[k] * s2 + dys2[k] * c2;
    }
  }

  // Green's theorem over boundary of (A ∩ B)
  float acc = 0.0f;
#pragma unroll
  for (int k = 0; k < 4; ++k) {
    const int kn = (k + 1) & 3;
    {
      const float dx = Ax[kn] - Ax[k], dy = Ay[kn] - Ay[k];
      const float len = clip_len(Ax[k], Ay[k], dx, dy, a2x, a2y, c2, s2, hw2, hh2);
      acc += (Ax[k] * dy - Ay[k] * dx) * len;
    }
    {
      const float dx = Bx[kn] - Bx[k], dy = By[kn] - By[k];
      const float len = clip_len(Bx[k], By[k], dx, dy, a1x, a1y, c1, s1, hw1, hh1);
      acc += (Bx[k] * dy - By[k] * dx) * len;
    }
  }
  const float inter = fmaxf(0.5f * acc, 0.0f);

  const float uni = w1 * h1 + w2 * h2 - inter;
  float iou = inter * __builtin_amdgcn_rcpf(uni);
  iou = fmaxf(iou, EPS_IOU);
  return 1.0f - iou * iou * iou;  // alpha = 3
}

__global__ __launch_bounds__(256) void rot_iou_loss_kernel(
    const float* __restrict__ pred, const float* __restrict__ target,
    float* __restrict__ out, int n, float inv_n) {
  // 2 * 2560 floats = 20480 B -> exactly 8 blocks/CU on 160 KiB LDS
  __shared__ float lp[EPB * 5];
  __shared__ float lt[EPB * 5];

  const int tid = threadIdx.x;
  const long base5 = (long)blockIdx.x * (EPB * 5);
  const long total5 = (long)n * 5;

  // ---- coalesced staging: 640 float4 per array ----
  const float4* p4 = (const float4*)(pred + base5);
  const float4* t4 = (const float4*)(target + base5);
#pragma unroll
  for (int it = 0; it < 3; ++it) {
    const int idx4 = it * BLOCK + tid;
    if (idx4 < EPB * 5 / 4) {
      const long g = base5 + (long)idx4 * 4;
      if (g + 3 < total5) {
        ((float4*)lp)[idx4] = p4[idx4];
        ((float4*)lt)[idx4] = t4[idx4];
      } else {
#pragma unroll
        for (int k = 0; k < 4; ++k) {
          const bool ok = (g + k) < total5;
          lp[idx4 * 4 + k] = ok ? pred[g + k] : 0.0f;
          lt[idx4 * 4 + k] = ok ? target[g + k] : 0.0f;
        }
      }
    }
  }
  __syncthreads();

  // ---- compute 2 elements per thread: t and t+256 (2-way LDS aliasing = free)
  float loss = 0.0f;
#pragma unroll
  for (int e = 0; e < 2; ++e) {
    const int local = tid + e * BLOCK;
    const long gi = (long)blockIdx.x * EPB + local;
    if (gi < n) loss += pair_loss(&lp[local * 5], &lt[local * 5]);
  }

  // ---- reduction: wave shuffle -> LDS (reuse lp) -> one atomic per block ----
#pragma unroll
  for (int off = 32; off > 0; off >>= 1) loss += __shfl_down(loss, off, 64);

  __syncthreads();  // done reading lp before reuse
  const int lane = tid & 63;
  const int wid = tid >> 6;
  if (lane == 0) lp[wid] = loss;
  __syncthreads();
  if (tid == 0) {
    const float bsum = lp[0] + lp[1] + lp[2] + lp[3];
    atomicAdd(out, bsum * inv_n);
  }
}

extern "C" void kernel_launch(void* const* d_in, const int* in_sizes, int n_in,
                              void* d_out, int out_size, void* d_ws, size_t ws_size,
                              hipStream_t stream) {
  const float* pred = (const float*)d_in[0];
  const float* target = (const float*)d_in[1];
  float* out = (float*)d_out;
  const int n = in_sizes[0] / 5;

  zero_out_kernel<<<1, 1, 0, stream>>>(out);
  const int grid = (n + EPB - 1) / EPB;
  rot_iou_loss_kernel<<<grid, BLOCK, 0, stream>>>(pred, target, out, n,
                                                  1.0f / (float)n);
}

// Round 4
// 89.997 us; speedup vs baseline: 11.7662x; 1.1412x over previous
//
#include <hip/hip_runtime.h>
#include <math.h>

#define EPS_IOU 1e-6f
#define BLOCK 256
#define BPT 4                    // boxes per thread
#define EPB (BLOCK * BPT)        // 1024 boxes per block

// Clip edge p0 + t*d, t in [0,1], against rotated rect (center rc, axes
// u=(ux,uy), v=(-uy,ux), half-extents hw,hh). Returns clipped length fraction.
__device__ __forceinline__ float clip_len(float p0x, float p0y, float dx, float dy,
                                          float rcx, float rcy, float ux, float uy,
                                          float hw, float hh) {
  const float rx = p0x - rcx, ry = p0y - rcy;
  const float bu = rx * ux + ry * uy;
  const float bv = -rx * uy + ry * ux;
  const float au = dx * ux + dy * uy;
  const float av = -dx * uy + dy * ux;
  const float iu = __builtin_amdgcn_rcpf(au);  // +-inf when au == 0
  const float iv = __builtin_amdgcn_rcpf(av);
  const float t0 = (-hw - bu) * iu;
  const float t1 = (hw - bu) * iu;
  const float t2 = (-hh - bv) * iv;
  const float t3 = (hh - bv) * iv;
  // IEEE fmin/fmax drop NaN (0*inf grazing) -> empty interval, measure-zero.
  const float lo = fmaxf(fmaxf(fminf(t0, t1), fminf(t2, t3)), 0.0f);
  const float hi = fminf(fminf(fmaxf(t0, t1), fmaxf(t2, t3)), 1.0f);
  return fmaxf(hi - lo, 0.0f);
}

__device__ __forceinline__ float pair_loss(const float* b1, const float* b2) {
  const float x1 = b1[0], y1 = b1[1], w1 = b1[2], h1 = b1[3], t1 = b1[4];
  const float x2 = b2[0], y2 = b2[1], w2 = b2[2], h2 = b2[3], t2 = b2[4];

  float s1, c1, s2, c2;
  __sincosf(t1, &s1, &c1);
  __sincosf(t2, &s2, &c2);

  // common origin near both boxes for fp32 headroom in cross products
  const float ox = 0.5f * (x1 + x2), oy = 0.5f * (y1 + y2);
  const float a1x = x1 - ox, a1y = y1 - oy;
  const float a2x = x2 - ox, a2y = y2 - oy;

  const float hw1 = 0.5f * w1, hh1 = 0.5f * h1;
  const float hw2 = 0.5f * w2, hh2 = 0.5f * h2;

  float Ax[4], Ay[4], Bx[4], By[4];
  {
    const float dxs1[4] = {-hw1, hw1, hw1, -hw1};
    const float dys1[4] = {-hh1, -hh1, hh1, hh1};
    const float dxs2[4] = {-hw2, hw2, hw2, -hw2};
    const float dys2[4] = {-hh2, -hh2, hh2, hh2};
#pragma unroll
    for (int k = 0; k < 4; ++k) {
      Ax[k] = a1x + dxs1[k] * c1 - dys1[k] * s1;
      Ay[k] = a1y + dxs1[k] * s1 + dys1[k] * c1;
      Bx[k] = a2x + dxs2[k] * c2 - dys2[k] * s2;
      By[k] = a2y + dxs2[k] * s2 + dys2[k] * c2;
    }
  }

  // Green's theorem over boundary of (A ∩ B)
  float acc = 0.0f;
#pragma unroll
  for (int k = 0; k < 4; ++k) {
    const int kn = (k + 1) & 3;
    {
      const float dx = Ax[kn] - Ax[k], dy = Ay[kn] - Ay[k];
      const float len = clip_len(Ax[k], Ay[k], dx, dy, a2x, a2y, c2, s2, hw2, hh2);
      acc += (Ax[k] * dy - Ay[k] * dx) * len;
    }
    {
      const float dx = Bx[kn] - Bx[k], dy = By[kn] - By[k];
      const float len = clip_len(Bx[k], By[k], dx, dy, a1x, a1y, c1, s1, hw1, hh1);
      acc += (Bx[k] * dy - By[k] * dx) * len;
    }
  }
  const float inter = fmaxf(0.5f * acc, 0.0f);

  const float uni = w1 * h1 + w2 * h2 - inter;
  float iou = inter * __builtin_amdgcn_rcpf(uni);
  iou = fmaxf(iou, EPS_IOU);
  return 1.0f - iou * iou * iou;  // alpha = 3
}

__global__ __launch_bounds__(256) void rot_iou_loss_kernel(
    const float* __restrict__ pred, const float* __restrict__ target,
    float* __restrict__ block_sums, int n) {
  const int tid = threadIdx.x;
  const long g0 = ((long)blockIdx.x * BLOCK + tid) * BPT;  // first box index

  float loss = 0.0f;
  if (g0 + BPT - 1 < n) {
    // fast path: 4 boxes = 20 floats = 5 aligned float4 loads per array
    float fp[20], ft[20];
    const float4* p4 = (const float4*)(pred + g0 * 5);
    const float4* t4 = (const float4*)(target + g0 * 5);
#pragma unroll
    for (int q = 0; q < 5; ++q) {
      ((float4*)fp)[q] = p4[q];
      ((float4*)ft)[q] = t4[q];
    }
#pragma unroll
    for (int j = 0; j < BPT; ++j) loss += pair_loss(&fp[j * 5], &ft[j * 5]);
  } else {
    // tail: guarded scalar loads (only last wave of last block diverges)
#pragma unroll
    for (int j = 0; j < BPT; ++j) {
      const long gi = g0 + j;
      if (gi < n) {
        float bp[5], bt[5];
#pragma unroll
        for (int k = 0; k < 5; ++k) {
          bp[k] = pred[gi * 5 + k];
          bt[k] = target[gi * 5 + k];
        }
        loss += pair_loss(bp, bt);
      }
    }
  }

  // reduction: wave shuffle -> LDS -> per-block partial sum (no atomics)
#pragma unroll
  for (int off = 32; off > 0; off >>= 1) loss += __shfl_down(loss, off, 64);

  __shared__ float wsum[4];
  const int lane = tid & 63;
  const int wid = tid >> 6;
  if (lane == 0) wsum[wid] = loss;
  __syncthreads();
  if (tid == 0) {
    block_sums[blockIdx.x] = wsum[0] + wsum[1] + wsum[2] + wsum[3];
  }
}

__global__ __launch_bounds__(256) void final_reduce_kernel(
    const float* __restrict__ block_sums, float* __restrict__ out, int nb,
    float inv_n) {
  const int tid = threadIdx.x;
  float s = 0.0f;
  for (int i = tid; i < nb; i += 256) s += block_sums[i];
#pragma unroll
  for (int off = 32; off > 0; off >>= 1) s += __shfl_down(s, off, 64);

  __shared__ float wsum[4];
  const int lane = tid & 63;
  const int wid = tid >> 6;
  if (lane == 0) wsum[wid] = s;
  __syncthreads();
  if (tid == 0) out[0] = (wsum[0] + wsum[1] + wsum[2] + wsum[3]) * inv_n;
}

extern "C" void kernel_launch(void* const* d_in, const int* in_sizes, int n_in,
                              void* d_out, int out_size, void* d_ws, size_t ws_size,
                              hipStream_t stream) {
  const float* pred = (const float*)d_in[0];
  const float* target = (const float*)d_in[1];
  float* out = (float*)d_out;
  float* bsums = (float*)d_ws;
  const int n = in_sizes[0] / 5;

  const int grid = (n + EPB - 1) / EPB;
  rot_iou_loss_kernel<<<grid, BLOCK, 0, stream>>>(pred, target, bsums, n);
  final_reduce_kernel<<<1, BLOCK, 0, stream>>>(bsums, out, grid,
                                               1.0f / (float)n);
}